// Round 2
// baseline (453.088 us; speedup 1.0000x reference)
//
#include <hip/hip_runtime.h>

typedef __attribute__((ext_vector_type(8))) short short8;
typedef __attribute__((ext_vector_type(4))) short short4v;
typedef __attribute__((ext_vector_type(4))) float f32x4;
typedef __attribute__((ext_vector_type(4))) unsigned int u32x4;
typedef __attribute__((ext_vector_type(2))) unsigned int u32x2;

#define MFMA16x32(A, B, C) \
  __builtin_amdgcn_mfma_f32_16x16x32_bf16((A), (B), (C), 0, 0, 0)

// Legacy K=16 bf16 MFMA (2-reg A/B). B-operand k = quad*4+j matches the
// S^T C/D layout (key = quad*4+reg) -> P feeds PV directly from registers.
#if defined(__has_builtin)
#if __has_builtin(__builtin_amdgcn_mfma_f32_16x16x16bf16_1k)
#define HAVE_MFMA_1K 1
#endif
#endif

__device__ __forceinline__ f32x4 mfma16x16(short4v a, short4v b, f32x4 c) {
#ifdef HAVE_MFMA_1K
  return __builtin_amdgcn_mfma_f32_16x16x16bf16_1k(a, b, c, 0, 0, 0);
#else
  f32x4 d;
  asm("v_mfma_f32_16x16x16_bf16 %0, %1, %2, %3"
      : "=v"(d)
      : "v"(a), "v"(b), "v"(c));
  return d;
#endif
}

__device__ __forceinline__ unsigned int fbits(float f) {
  return __builtin_bit_cast(unsigned int, f);
}
// pack two floats -> two bf16 (truncate): low ushort = a, high = b
__device__ __forceinline__ unsigned int pack_bf16(float a, float b) {
  return __builtin_amdgcn_perm(fbits(b), fbits(a), 0x07060302u);
}
__device__ __forceinline__ unsigned short bf16_rne(float f) {
  unsigned int u = fbits(f);
  return (unsigned short)((u + 0x8000u) >> 16);
}

// ---------------------------------------------------------------------------
// Kernel 0: x fp32 -> bf16 (so proj A-frags are direct short8 loads).
// ---------------------------------------------------------------------------
__global__ __launch_bounds__(256) void xconv_kernel(
    const float* __restrict__ x, unsigned short* __restrict__ xb) {
  const size_t i = ((size_t)blockIdx.x * 256 + threadIdx.x) * 4;
  const float4 f = *(const float4*)(x + i);
  u32x2 u = {(unsigned int)bf16_rne(f.x) | ((unsigned int)bf16_rne(f.y) << 16),
             (unsigned int)bf16_rne(f.z) | ((unsigned int)bf16_rne(f.w) << 16)};
  *(u32x2*)(xb + i) = u;
}

// ---------------------------------------------------------------------------
// Kernel 1: W (256x256 fp32) -> WT (bf16, [n][k]) for all three weights.
// ---------------------------------------------------------------------------
__global__ __launch_bounds__(256) void wtrans_kernel(
    const float* __restrict__ Wq, const float* __restrict__ Wk,
    const float* __restrict__ Wv, unsigned short* __restrict__ WT) {
  __shared__ float tile[32][33];
  const int bid = blockIdx.x;
  const int g = bid / 64, rem = bid % 64;
  const int k0 = (rem >> 3) * 32, n0 = (rem & 7) * 32;
  const float* W = (g == 0) ? Wq : (g == 1) ? Wk : Wv;
  const int t = threadIdx.x;
  {
    const int kr = t >> 3, nc = (t & 7) * 4;
    const float4 f = *(const float4*)(W + (size_t)(k0 + kr) * 256 + n0 + nc);
    tile[kr][nc + 0] = f.x; tile[kr][nc + 1] = f.y;
    tile[kr][nc + 2] = f.z; tile[kr][nc + 3] = f.w;
  }
  __syncthreads();
  {
    const int nr = t >> 3, kc = (t & 7) * 4;
    unsigned int u0 = (unsigned int)bf16_rne(tile[kc + 0][nr]) |
                      ((unsigned int)bf16_rne(tile[kc + 1][nr]) << 16);
    unsigned int u1 = (unsigned int)bf16_rne(tile[kc + 2][nr]) |
                      ((unsigned int)bf16_rne(tile[kc + 3][nr]) << 16);
    u32x2 u = {u0, u1};
    *(u32x2*)(WT + (size_t)g * 65536 + (size_t)(n0 + nr) * 256 + k0 + kc) = u;
  }
}

// ---------------------------------------------------------------------------
// Kernel 2: fused QKV projection GEMM. xb[16384,256] bf16 @ W[256,256] -> bf16.
// Tile: 128(M) x 128(N), K=256, 4 waves; wave = 2 strips of 16 rows x 128 cols.
// Q gets 1/sqrt(dk) folded in; V written transposed: VT[(b*8+h)*32+d][n].
// ---------------------------------------------------------------------------
__global__ __launch_bounds__(256, 4) void proj_kernel(
    const unsigned short* __restrict__ xb, const unsigned short* __restrict__ WT,
    unsigned short* __restrict__ Q, unsigned short* __restrict__ K,
    unsigned short* __restrict__ VT) {
  const int tid = threadIdx.x;
  const int w = tid >> 6, lane = tid & 63, l15 = lane & 15, quad = lane >> 4;
  const int bid = blockIdx.x;
  const int mtile = bid / 6, nt = bid % 6;
  const int g = nt >> 1, n0 = (nt & 1) * 128;
  const int m0 = mtile * 128 + w * 32;
  const unsigned short* xp = xb + (size_t)(m0 + l15) * 256 + quad * 8;
  const unsigned short* wp =
      WT + (size_t)g * 65536 + (size_t)(n0 + l15) * 256 + quad * 8;
  const f32x4 zero = {0.f, 0.f, 0.f, 0.f};
  f32x4 acc[2][8];
#pragma unroll
  for (int s = 0; s < 2; s++)
#pragma unroll
    for (int c = 0; c < 8; c++) acc[s][c] = zero;

  for (int k0 = 0; k0 < 256; k0 += 32) {
    short8 a[2];
#pragma unroll
    for (int s = 0; s < 2; s++)
      a[s] = *(const short8*)(xp + (size_t)s * 4096 + k0);
    short8 bfrag[8];
#pragma unroll
    for (int c = 0; c < 8; c++)
      bfrag[c] = *(const short8*)(wp + (size_t)c * 4096 + k0);
#pragma unroll
    for (int s = 0; s < 2; s++)
#pragma unroll
      for (int c = 0; c < 8; c++)
        acc[s][c] = MFMA16x32(a[s], bfrag[c], acc[s][c]);
  }

  if (g < 2) {
    unsigned short* O = g ? K : Q;
    const float scale = g ? 1.0f : 0.17677669529663688f;  // 1/sqrt(32) into Q
#pragma unroll
    for (int s = 0; s < 2; s++)
#pragma unroll
      for (int c = 0; c < 8; c++)
#pragma unroll
        for (int r = 0; r < 4; r++) {
          const int row = m0 + s * 16 + quad * 4 + r;
          const int col = n0 + c * 16 + l15;
          O[(size_t)row * 256 + col] = bf16_rne(acc[s][c][r] * scale);
        }
  } else {
    // V: C/D rows (quad*4+r) = consecutive n -> contiguous in VT; 8B stores.
#pragma unroll
    for (int s = 0; s < 2; s++)
#pragma unroll
      for (int c = 0; c < 8; c++) {
        const int col = n0 + c * 16 + l15;  // 0..255 = h*32 + d
        const int hh = col >> 5, dloc = col & 31;
        const int row = m0 + s * 16 + quad * 4;
        const int bb = row >> 12, nn = row & 4095;
        u32x2 pk = {pack_bf16(acc[s][c][0], acc[s][c][1]),
                    pack_bf16(acc[s][c][2], acc[s][c][3])};
        *(u32x2*)(VT + (size_t)((bb * 8 + hh) * 32 + dloc) * 4096 + nn) = pk;
      }
  }
}

// ---------------------------------------------------------------------------
// Kernel 3: attention, zero-LDS. Per block: one (b,h), 128 q-rows; per wave
// 32 q (2 strips of 16). K-tile 64/iter.
// S^T = K·Q^T via 16x16x32 (C/D: row=key=quad*4+reg, col=q=l15); leaky+pack
// in regs; P^T feeds PV directly as the B-operand of 16x16x16 (k=quad*4+j).
// out^T accum: row=d (4 consecutive per lane) -> f32x4 epilogue stores.
// ---------------------------------------------------------------------------
__global__ __launch_bounds__(256, 4) void attn_kernel(
    const unsigned short* __restrict__ Q, const unsigned short* __restrict__ K,
    const unsigned short* __restrict__ VT, float* __restrict__ out) {
  const int tid = threadIdx.x;
  const int w = tid >> 6, lane = tid & 63, l15 = lane & 15, quad = lane >> 4;
  const int bid = blockIdx.x;
  const int bh = bid >> 5, qt = bid & 31;
  const int b = bh >> 3, h = bh & 7;
  const int qbase = qt * 128 + w * 32;

  const unsigned short* Qp =
      Q + (size_t)(b * 4096 + qbase + l15) * 256 + h * 32 + quad * 8;
  short8 qf[2];
#pragma unroll
  for (int s = 0; s < 2; s++) qf[s] = *(const short8*)(Qp + (size_t)s * 4096);

  const unsigned short* Kp =
      K + (size_t)(b * 4096 + l15) * 256 + h * 32 + quad * 8;
  const unsigned short* Vp =
      VT + (size_t)(bh * 32 + l15) * 4096 + quad * 4;  // row = d (l15 + dt*16)

  const f32x4 zero = {0.f, 0.f, 0.f, 0.f};
  f32x4 acc[2][2];  // [qstrip][dtile] : out^T, col=q=l15, row=d=dt*16+quad*4+r
#pragma unroll
  for (int s = 0; s < 2; s++) {
    acc[s][0] = zero;
    acc[s][1] = zero;
  }

  for (int kb = 0; kb < 4096; kb += 64) {
    short8 kf[4];
#pragma unroll
    for (int c = 0; c < 4; c++)
      kf[c] = *(const short8*)(Kp + (size_t)(kb + c * 16) * 256);
    short4v vf[2][4];  // A-operand of PV^T: m=d=l15(+16dt), k=key=quad*4+j
#pragma unroll
    for (int dt = 0; dt < 2; dt++)
#pragma unroll
      for (int c = 0; c < 4; c++)
        vf[dt][c] =
            *(const short4v*)(Vp + (size_t)dt * 16 * 4096 + kb + c * 16);

#pragma unroll
    for (int s = 0; s < 2; s++) {
#pragma unroll
      for (int c = 0; c < 4; c++) {
        f32x4 st = MFMA16x32(kf[c], qf[s], zero);  // S^T 16key x 16q
        float t0 = fmaxf(st[0], 0.2f * st[0]);     // Q pre-scaled by 1/sqrt(dk)
        float t1 = fmaxf(st[1], 0.2f * st[1]);
        float t2 = fmaxf(st[2], 0.2f * st[2]);
        float t3 = fmaxf(st[3], 0.2f * st[3]);
        u32x2 pk = {pack_bf16(t0, t1), pack_bf16(t2, t3)};
        const short4v pb = __builtin_bit_cast(short4v, pk);
#pragma unroll
        for (int dt = 0; dt < 2; dt++)
          acc[s][dt] = mfma16x16(vf[dt][c], pb, acc[s][dt]);
      }
    }
  }

  // Epilogue: out[b][q][h*32 + d]; lane holds q=l15(+16s), d=dt*16+quad*4+r
  // -> 4 consecutive floats per store.
#pragma unroll
  for (int s = 0; s < 2; s++)
#pragma unroll
    for (int dt = 0; dt < 2; dt++)
      *(f32x4*)(out + (size_t)(b * 4096 + qbase + s * 16 + l15) * 256 + h * 32 +
                dt * 16 + quad * 4) = acc[s][dt];
}

// ---------------------------------------------------------------------------
extern "C" void kernel_launch(void* const* d_in, const int* in_sizes, int n_in,
                              void* d_out, int out_size, void* d_ws,
                              size_t ws_size, hipStream_t stream) {
  const float* x = (const float*)d_in[0];
  const float* Wq = (const float*)d_in[1];
  const float* Wk = (const float*)d_in[2];
  const float* Wv = (const float*)d_in[3];
  float* out = (float*)d_out;

  // Workspace (bf16): Q | K | VT | xb | WT   (~33 MB)
  unsigned short* ws = (unsigned short*)d_ws;
  unsigned short* Qb = ws;                 // 16384*256
  unsigned short* Kb = ws + 4194304;       // 16384*256
  unsigned short* VTb = ws + 2 * 4194304;  // 32 heads * 32 d * 4096 n
  unsigned short* xbb = ws + 3 * 4194304;  // 16384*256
  unsigned short* WTb = ws + 4 * 4194304;  // 3 * 256 * 256

  xconv_kernel<<<4096, 256, 0, stream>>>(x, xbb);
  wtrans_kernel<<<192, 256, 0, stream>>>(Wq, Wk, Wv, WTb);
  proj_kernel<<<768, 256, 0, stream>>>(xbb, WTb, Qb, Kb, VTb);
  attn_kernel<<<1024, 256, 0, stream>>>(Qb, Kb, VTb, out);
}

// Round 3
// 304.752 us; speedup vs baseline: 1.4867x; 1.4867x over previous
//
#include <hip/hip_runtime.h>

typedef __attribute__((ext_vector_type(8))) short short8;
typedef __attribute__((ext_vector_type(4))) short short4v;
typedef __attribute__((ext_vector_type(4))) float f32x4;
typedef __attribute__((ext_vector_type(2))) unsigned int u32x2;

#define MFMA16x32(A, B, C) \
  __builtin_amdgcn_mfma_f32_16x16x32_bf16((A), (B), (C), 0, 0, 0)

// Legacy K=16 bf16 MFMA (2-reg A/B). B-operand k = quad*4+j matches the
// S^T C/D layout (key = quad*4+reg) -> P feeds PV directly from registers.
#if defined(__has_builtin)
#if __has_builtin(__builtin_amdgcn_mfma_f32_16x16x16bf16_1k)
#define HAVE_MFMA_1K 1
#endif
#endif

__device__ __forceinline__ f32x4 mfma16x16(short4v a, short4v b, f32x4 c) {
#ifdef HAVE_MFMA_1K
  return __builtin_amdgcn_mfma_f32_16x16x16bf16_1k(a, b, c, 0, 0, 0);
#else
  f32x4 d;
  asm("v_mfma_f32_16x16x16_bf16 %0, %1, %2, %3"
      : "=v"(d)
      : "v"(a), "v"(b), "v"(c));
  return d;
#endif
}

__device__ __forceinline__ unsigned int fbits(float f) {
  return __builtin_bit_cast(unsigned int, f);
}
// pack two floats -> two bf16 (truncate): low ushort = a, high = b
__device__ __forceinline__ unsigned int pack_bf16(float a, float b) {
  return __builtin_amdgcn_perm(fbits(b), fbits(a), 0x07060302u);
}
__device__ __forceinline__ unsigned short bf16_rne(float f) {
  unsigned int u = fbits(f);
  return (unsigned short)((u + 0x8000u) >> 16);
}

// ---------------------------------------------------------------------------
// Kernel 0: x fp32 -> bf16 (so proj A-frags are direct short8 loads).
// ---------------------------------------------------------------------------
__global__ __launch_bounds__(256) void xconv_kernel(
    const float* __restrict__ x, unsigned short* __restrict__ xb) {
  const size_t i = ((size_t)blockIdx.x * 256 + threadIdx.x) * 4;
  const float4 f = *(const float4*)(x + i);
  u32x2 u = {(unsigned int)bf16_rne(f.x) | ((unsigned int)bf16_rne(f.y) << 16),
             (unsigned int)bf16_rne(f.z) | ((unsigned int)bf16_rne(f.w) << 16)};
  *(u32x2*)(xb + i) = u;
}

// ---------------------------------------------------------------------------
// Kernel 1: W (256x256 fp32) -> WT (bf16, [n][k]) for all three weights.
// ---------------------------------------------------------------------------
__global__ __launch_bounds__(256) void wtrans_kernel(
    const float* __restrict__ Wq, const float* __restrict__ Wk,
    const float* __restrict__ Wv, unsigned short* __restrict__ WT) {
  __shared__ float tile[32][33];
  const int bid = blockIdx.x;
  const int g = bid / 64, rem = bid % 64;
  const int k0 = (rem >> 3) * 32, n0 = (rem & 7) * 32;
  const float* W = (g == 0) ? Wq : (g == 1) ? Wk : Wv;
  const int t = threadIdx.x;
  {
    const int kr = t >> 3, nc = (t & 7) * 4;
    const float4 f = *(const float4*)(W + (size_t)(k0 + kr) * 256 + n0 + nc);
    tile[kr][nc + 0] = f.x; tile[kr][nc + 1] = f.y;
    tile[kr][nc + 2] = f.z; tile[kr][nc + 3] = f.w;
  }
  __syncthreads();
  {
    const int nr = t >> 3, kc = (t & 7) * 4;
    unsigned int u0 = (unsigned int)bf16_rne(tile[kc + 0][nr]) |
                      ((unsigned int)bf16_rne(tile[kc + 1][nr]) << 16);
    unsigned int u1 = (unsigned int)bf16_rne(tile[kc + 2][nr]) |
                      ((unsigned int)bf16_rne(tile[kc + 3][nr]) << 16);
    u32x2 u = {u0, u1};
    *(u32x2*)(WT + (size_t)g * 65536 + (size_t)(n0 + nr) * 256 + k0 + kc) = u;
  }
}

// ---------------------------------------------------------------------------
// Kernel 2: fused QKV projection GEMM, register-prefetched.
// For Q/K the MFMA operands are SWAPPED (A=W^T frag, B=x frag) so the C/D
// reg-dim (quad*4+r) lands on the dk axis -> packed 8B stores, natural [n][dk]
// layout. For V the original orientation keeps the reg-dim on n -> VT[d][n]
// packed stores.
// ---------------------------------------------------------------------------
__global__ __launch_bounds__(256, 3) void proj_kernel(
    const unsigned short* __restrict__ xb, const unsigned short* __restrict__ WT,
    unsigned short* __restrict__ Q, unsigned short* __restrict__ K,
    unsigned short* __restrict__ VT) {
  const int tid = threadIdx.x;
  const int w = tid >> 6, lane = tid & 63, l15 = lane & 15, quad = lane >> 4;
  const int bid = blockIdx.x;
  const int mtile = bid / 6, nt = bid % 6;
  const int g = nt >> 1, n0 = (nt & 1) * 128;
  const int m0 = mtile * 128 + w * 32;
  const unsigned short* xp = xb + (size_t)(m0 + l15) * 256 + quad * 8;
  const unsigned short* wp =
      WT + (size_t)g * 65536 + (size_t)(n0 + l15) * 256 + quad * 8;
  const f32x4 zero = {0.f, 0.f, 0.f, 0.f};
  f32x4 acc[2][8];
#pragma unroll
  for (int s = 0; s < 2; s++)
#pragma unroll
    for (int c = 0; c < 8; c++) acc[s][c] = zero;

  short8 a_c[2], b_c[8], a_n[2], b_n[8];
#pragma unroll
  for (int s = 0; s < 2; s++) a_c[s] = *(const short8*)(xp + (size_t)s * 4096);
#pragma unroll
  for (int c = 0; c < 8; c++) b_c[c] = *(const short8*)(wp + (size_t)c * 4096);

  for (int k0 = 0; k0 < 256; k0 += 32) {
    const int kn = (k0 + 32) & 255;  // wraps; avoids OOB w/o a branch
#pragma unroll
    for (int s = 0; s < 2; s++)
      a_n[s] = *(const short8*)(xp + (size_t)s * 4096 + kn);
#pragma unroll
    for (int c = 0; c < 8; c++)
      b_n[c] = *(const short8*)(wp + (size_t)c * 4096 + kn);
    if (g < 2) {
#pragma unroll
      for (int s = 0; s < 2; s++)
#pragma unroll
        for (int c = 0; c < 8; c++)
          acc[s][c] = MFMA16x32(b_c[c], a_c[s], acc[s][c]);  // swapped
    } else {
#pragma unroll
      for (int s = 0; s < 2; s++)
#pragma unroll
        for (int c = 0; c < 8; c++)
          acc[s][c] = MFMA16x32(a_c[s], b_c[c], acc[s][c]);
    }
#pragma unroll
    for (int s = 0; s < 2; s++) a_c[s] = a_n[s];
#pragma unroll
    for (int c = 0; c < 8; c++) b_c[c] = b_n[c];
  }

  if (g < 2) {
    // Swapped orientation: lane tile (s,c) holds rows m0+s*16+l15 (x-row),
    // cols n0+c*16+quad*4+r (dk) -> 4 consecutive output cols: 8B stores.
    unsigned short* O = g ? K : Q;
    const float sc = g ? 1.0f : 0.17677669529663688f;  // 1/sqrt(32) into Q
#pragma unroll
    for (int s = 0; s < 2; s++)
#pragma unroll
      for (int c = 0; c < 8; c++) {
        const int row = m0 + s * 16 + l15;
        const int col = n0 + c * 16 + quad * 4;
        u32x2 pk = {pack_bf16(acc[s][c][0] * sc, acc[s][c][1] * sc),
                    pack_bf16(acc[s][c][2] * sc, acc[s][c][3] * sc)};
        *(u32x2*)(O + (size_t)row * 256 + col) = pk;
      }
  } else {
    // Original orientation: reg-dim = consecutive n -> contiguous in VT.
#pragma unroll
    for (int s = 0; s < 2; s++)
#pragma unroll
      for (int c = 0; c < 8; c++) {
        const int col = n0 + c * 16 + l15;  // 0..255 = h*32 + d
        const int hh = col >> 5, dloc = col & 31;
        const int row = m0 + s * 16 + quad * 4;
        const int bb = row >> 12, nn = row & 4095;
        u32x2 pk = {pack_bf16(acc[s][c][0], acc[s][c][1]),
                    pack_bf16(acc[s][c][2], acc[s][c][3])};
        *(u32x2*)(VT + (size_t)((bb * 8 + hh) * 32 + dloc) * 4096 + nn) = pk;
      }
  }
}

// ---------------------------------------------------------------------------
// Kernel 3: attention, key-split waves. Block = (b,h) x 64 q-rows; wave w owns
// keys [kb + w*16, kb + w*16 + 16) each iter (kb += 64). Each wave accumulates
// partial O over all 64 q (4 strips); LDS reduction across the 4 waves at the
// end. No barriers in the loop; kf/vf register-prefetched one iter ahead.
// bh = bid & 31 so all 64 q-blocks of one (b,h) land on one XCD (L2-resident
// 512 KB K+V slice).
// ---------------------------------------------------------------------------
__global__ __launch_bounds__(256, 4) void attn_kernel(
    const unsigned short* __restrict__ Q, const unsigned short* __restrict__ K,
    const unsigned short* __restrict__ VT, float* __restrict__ out) {
  __shared__ __align__(16) float red[4][64][36];
  const int tid = threadIdx.x;
  const int w = tid >> 6, lane = tid & 63, l15 = lane & 15, quad = lane >> 4;
  const int bid = blockIdx.x;
  const int bh = bid & 31, qt = bid >> 5;
  const int b = bh >> 3, h = bh & 7;
  const int qbase = qt * 64;

  const unsigned short* Qp =
      Q + (size_t)(b * 4096 + qbase + l15) * 256 + h * 32 + quad * 8;
  short8 qf[4];
#pragma unroll
  for (int s = 0; s < 4; s++) qf[s] = *(const short8*)(Qp + (size_t)s * 4096);

  const unsigned short* Kp =
      K + (size_t)(b * 4096 + w * 16 + l15) * 256 + h * 32 + quad * 8;
  const unsigned short* Vp =
      VT + (size_t)(bh * 32 + l15) * 4096 + w * 16 + quad * 4;

  const f32x4 zero = {0.f, 0.f, 0.f, 0.f};
  f32x4 acc[4][2];  // [qstrip][dtile]: partial O^T over this wave's keys
#pragma unroll
  for (int s = 0; s < 4; s++) {
    acc[s][0] = zero;
    acc[s][1] = zero;
  }

  short8 kf_c = *(const short8*)(Kp);
  short4v vf_c[2] = {*(const short4v*)(Vp), *(const short4v*)(Vp + 65536)};

  for (int kb = 0; kb < 4096; kb += 64) {
    const int nkb = (kb + 64) & 4095;  // wraps; last prefetch stays in-bounds
    short8 kf_n = *(const short8*)(Kp + (size_t)nkb * 256);
    short4v vf_n0 = *(const short4v*)(Vp + nkb);
    short4v vf_n1 = *(const short4v*)(Vp + 65536 + nkb);

#pragma unroll
    for (int s = 0; s < 4; s++) {
      f32x4 st = MFMA16x32(kf_c, qf[s], zero);  // S^T 16key x 16q
      float t0 = fmaxf(st[0], 0.2f * st[0]);    // Q pre-scaled by 1/sqrt(dk)
      float t1 = fmaxf(st[1], 0.2f * st[1]);
      float t2 = fmaxf(st[2], 0.2f * st[2]);
      float t3 = fmaxf(st[3], 0.2f * st[3]);
      u32x2 pk = {pack_bf16(t0, t1), pack_bf16(t2, t3)};
      const short4v pb = __builtin_bit_cast(short4v, pk);
#pragma unroll
      for (int dt = 0; dt < 2; dt++)
        acc[s][dt] = mfma16x16(vf_c[dt], pb, acc[s][dt]);
    }
    kf_c = kf_n;
    vf_c[0] = vf_n0;
    vf_c[1] = vf_n1;
  }

  // Cross-wave reduction: O^T lane layout col=q=l15(+16s), row=d=dt*16+quad*4+r
#pragma unroll
  for (int s = 0; s < 4; s++)
#pragma unroll
    for (int dt = 0; dt < 2; dt++)
      *(f32x4*)&red[w][s * 16 + l15][dt * 16 + quad * 4] = acc[s][dt];
  __syncthreads();

  const int q = tid >> 2, dbase = (tid & 3) * 8;
  f32x4 s0 = *(const f32x4*)&red[0][q][dbase];
  f32x4 s1 = *(const f32x4*)&red[0][q][dbase + 4];
#pragma unroll
  for (int ww = 1; ww < 4; ww++) {
    s0 += *(const f32x4*)&red[ww][q][dbase];
    s1 += *(const f32x4*)&red[ww][q][dbase + 4];
  }
  float* op = out + (size_t)(b * 4096 + qbase + q) * 256 + h * 32 + dbase;
  *(f32x4*)op = s0;
  *(f32x4*)(op + 4) = s1;
}

// ---------------------------------------------------------------------------
extern "C" void kernel_launch(void* const* d_in, const int* in_sizes, int n_in,
                              void* d_out, int out_size, void* d_ws,
                              size_t ws_size, hipStream_t stream) {
  const float* x = (const float*)d_in[0];
  const float* Wq = (const float*)d_in[1];
  const float* Wk = (const float*)d_in[2];
  const float* Wv = (const float*)d_in[3];
  float* out = (float*)d_out;

  // Workspace (bf16): Q | K | VT | xb | WT   (~33.5 MB)
  unsigned short* ws = (unsigned short*)d_ws;
  unsigned short* Qb = ws;                 // 16384*256
  unsigned short* Kb = ws + 4194304;       // 16384*256
  unsigned short* VTb = ws + 2 * 4194304;  // 32 heads * 32 d * 4096 n
  unsigned short* xbb = ws + 3 * 4194304;  // 16384*256
  unsigned short* WTb = ws + 4 * 4194304;  // 3 * 256 * 256

  xconv_kernel<<<4096, 256, 0, stream>>>(x, xbb);
  wtrans_kernel<<<192, 256, 0, stream>>>(Wq, Wk, Wv, WTb);
  proj_kernel<<<768, 256, 0, stream>>>(xbb, WTb, Qb, Kb, VTb);
  attn_kernel<<<2048, 256, 0, stream>>>(Qb, Kb, VTb, out);
}

// Round 4
// 174.813 us; speedup vs baseline: 2.5918x; 1.7433x over previous
//
#include <hip/hip_runtime.h>

typedef __attribute__((ext_vector_type(8))) short short8;
typedef __attribute__((ext_vector_type(4))) short short4v;
typedef __attribute__((ext_vector_type(4))) float f32x4;
typedef __attribute__((ext_vector_type(2))) unsigned int u32x2;

#define MFMA16x32(A, B, C) \
  __builtin_amdgcn_mfma_f32_16x16x32_bf16((A), (B), (C), 0, 0, 0)

// Legacy K=16 bf16 MFMA (2-reg A/B). B-operand k = quad*4+j matches the
// S^T C/D layout (key = quad*4+reg) -> P feeds PV directly from registers.
#if defined(__has_builtin)
#if __has_builtin(__builtin_amdgcn_mfma_f32_16x16x16bf16_1k)
#define HAVE_MFMA_1K 1
#endif
#endif

__device__ __forceinline__ f32x4 mfma16x16(short4v a, short4v b, f32x4 c) {
#ifdef HAVE_MFMA_1K
  return __builtin_amdgcn_mfma_f32_16x16x16bf16_1k(a, b, c, 0, 0, 0);
#else
  f32x4 d;
  asm("v_mfma_f32_16x16x16_bf16 %0, %1, %2, %3"
      : "=v"(d)
      : "v"(a), "v"(b), "v"(c));
  return d;
#endif
}

// Async global->LDS, 16B/lane. Global addr is per-lane; LDS dest is the
// WAVE-UNIFORM base (HW scatters lane i -> base + i*16).
__device__ __forceinline__ void async_cp16(const unsigned short* g, void* l) {
  __builtin_amdgcn_global_load_lds(
      (const __attribute__((address_space(1))) unsigned int*)g,
      (__attribute__((address_space(3))) unsigned int*)l, 16, 0, 0);
}

__device__ __forceinline__ unsigned int fbits(float f) {
  return __builtin_bit_cast(unsigned int, f);
}
// pack two floats -> two bf16 (truncate): low ushort = a, high = b
__device__ __forceinline__ unsigned int pack_bf16(float a, float b) {
  return __builtin_amdgcn_perm(fbits(b), fbits(a), 0x07060302u);
}
__device__ __forceinline__ unsigned short bf16_rne(float f) {
  unsigned int u = fbits(f);
  return (unsigned short)((u + 0x8000u) >> 16);
}

// ---------------------------------------------------------------------------
// Kernel 0: x fp32 -> bf16.
// ---------------------------------------------------------------------------
__global__ __launch_bounds__(256) void xconv_kernel(
    const float* __restrict__ x, unsigned short* __restrict__ xb) {
  const size_t i = ((size_t)blockIdx.x * 256 + threadIdx.x) * 4;
  const float4 f = *(const float4*)(x + i);
  u32x2 u = {(unsigned int)bf16_rne(f.x) | ((unsigned int)bf16_rne(f.y) << 16),
             (unsigned int)bf16_rne(f.z) | ((unsigned int)bf16_rne(f.w) << 16)};
  *(u32x2*)(xb + i) = u;
}

// ---------------------------------------------------------------------------
// Kernel 1: W (256x256 fp32) -> WT (bf16, [n][k]) for all three weights.
// ---------------------------------------------------------------------------
__global__ __launch_bounds__(256) void wtrans_kernel(
    const float* __restrict__ Wq, const float* __restrict__ Wk,
    const float* __restrict__ Wv, unsigned short* __restrict__ WT) {
  __shared__ float tile[32][33];
  const int bid = blockIdx.x;
  const int g = bid / 64, rem = bid % 64;
  const int k0 = (rem >> 3) * 32, n0 = (rem & 7) * 32;
  const float* W = (g == 0) ? Wq : (g == 1) ? Wk : Wv;
  const int t = threadIdx.x;
  {
    const int kr = t >> 3, nc = (t & 7) * 4;
    const float4 f = *(const float4*)(W + (size_t)(k0 + kr) * 256 + n0 + nc);
    tile[kr][nc + 0] = f.x; tile[kr][nc + 1] = f.y;
    tile[kr][nc + 2] = f.z; tile[kr][nc + 3] = f.w;
  }
  __syncthreads();
  {
    const int nr = t >> 3, kc = (t & 7) * 4;
    unsigned int u0 = (unsigned int)bf16_rne(tile[kc + 0][nr]) |
                      ((unsigned int)bf16_rne(tile[kc + 1][nr]) << 16);
    unsigned int u1 = (unsigned int)bf16_rne(tile[kc + 2][nr]) |
                      ((unsigned int)bf16_rne(tile[kc + 3][nr]) << 16);
    u32x2 u = {u0, u1};
    *(u32x2*)(WT + (size_t)g * 65536 + (size_t)(n0 + nr) * 256 + k0 + kc) = u;
  }
}

// ---------------------------------------------------------------------------
// Kernel 2: fused QKV projection GEMM, LDS-staged (m97 pattern), BK=64 dbuf.
// 128m x 128n tile, 4 waves, wave = 32m x 128n. A=xb[m][k], B=WT[n][k], both
// staged via global_load_lds with 16B-seg XOR swizzle (conflict-free b128
// frag reads). Q/K written packed per head: QH/KH[bh][n][32] (Q pre-scaled by
// 1/sqrt(dk)); V written transposed: VT[bh*32+d][n].
// ---------------------------------------------------------------------------
__global__ __launch_bounds__(256, 2) void proj_kernel(
    const unsigned short* __restrict__ xb, const unsigned short* __restrict__ WT,
    unsigned short* __restrict__ QH, unsigned short* __restrict__ KH,
    unsigned short* __restrict__ VT) {
  __shared__ __align__(16) char smem[65536];  // dbuf x (A 16K + B 16K)
  const int tid = threadIdx.x;
  const int w = tid >> 6, lane = tid & 63, l15 = lane & 15, quad = lane >> 4;
  const int bid = blockIdx.x;
  const int mtile = bid / 6, nt = bid % 6;
  const int g = nt >> 1, n0 = (nt & 1) * 128;
  const int m0 = mtile * 128;

  // Staging: wave w covers tile-rows w*32..+32 (4 instrs of 8 rows each).
  // LDS row r holds global 16B-seg (u ^ (r&7)) at seg u (XOR swizzle).
  const int srow = lane >> 3, useg = lane & 7;
  const int swz = (useg ^ srow) * 8;  // shorts
  const unsigned short* aS = xb + (size_t)(m0 + w * 32 + srow) * 256 + swz;
  const unsigned short* bS =
      WT + (size_t)g * 65536 + (size_t)(n0 + w * 32 + srow) * 256 + swz;

#pragma unroll
  for (int j = 0; j < 4; j++) {  // preload k-tile 0 -> buf 0
    async_cp16(aS + j * 2048, smem + w * 4096 + j * 1024);
    async_cp16(bS + j * 2048, smem + 16384 + w * 4096 + j * 1024);
  }
  __syncthreads();

  const f32x4 zero = {0.f, 0.f, 0.f, 0.f};
  f32x4 acc[2][8];
#pragma unroll
  for (int s = 0; s < 2; s++)
#pragma unroll
    for (int c = 0; c < 8; c++) acc[s][c] = zero;

  const int sw = l15 & 7;
  for (int t = 0; t < 4; t++) {
    const int nb = t & 1;
    const int kn = ((t + 1) & 3) * 64;  // wraps; last prefetch harmless
#pragma unroll
    for (int j = 0; j < 4; j++) {
      async_cp16(aS + kn + j * 2048,
                 smem + (nb ^ 1) * 32768 + w * 4096 + j * 1024);
      async_cp16(bS + kn + j * 2048,
                 smem + (nb ^ 1) * 32768 + 16384 + w * 4096 + j * 1024);
    }
    const char* Ab = smem + nb * 32768;
    const char* Bb = Ab + 16384;
#pragma unroll
    for (int ks = 0; ks < 2; ks++) {
      const int seg = ((ks * 4 + quad) ^ sw) * 16;
      short8 af[2], bf[8];
#pragma unroll
      for (int s = 0; s < 2; s++)
        af[s] = *(const short8*)(Ab + (w * 32 + s * 16 + l15) * 128 + seg);
#pragma unroll
      for (int c = 0; c < 8; c++)
        bf[c] = *(const short8*)(Bb + (c * 16 + l15) * 128 + seg);
      if (g < 2) {
#pragma unroll
        for (int s = 0; s < 2; s++)
#pragma unroll
          for (int c = 0; c < 8; c++)
            acc[s][c] = MFMA16x32(bf[c], af[s], acc[s][c]);  // swapped
      } else {
#pragma unroll
        for (int s = 0; s < 2; s++)
#pragma unroll
          for (int c = 0; c < 8; c++)
            acc[s][c] = MFMA16x32(af[s], bf[c], acc[s][c]);
      }
    }
    __syncthreads();
  }

  if (g < 2) {
    // Swapped orientation: rows m0+w*32+s*16+l15 (seq), cols n0+c*16+quad*4
    // (+reg) = feature -> 4 consecutive dk: packed 8B stores into [bh][n][32].
    unsigned short* O = g ? KH : QH;
    const float sc = g ? 1.0f : 0.17677669529663688f;  // 1/sqrt(32) into Q
#pragma unroll
    for (int s = 0; s < 2; s++)
#pragma unroll
      for (int c = 0; c < 8; c++) {
        const int row = m0 + w * 32 + s * 16 + l15;
        const int col = n0 + c * 16 + quad * 4;
        const int bb = row >> 12, nn = row & 4095;
        const int hh = col >> 5, dl = col & 31;
        u32x2 pk = {pack_bf16(acc[s][c][0] * sc, acc[s][c][1] * sc),
                    pack_bf16(acc[s][c][2] * sc, acc[s][c][3] * sc)};
        *(u32x2*)(O + ((size_t)(bb * 8 + hh) * 4096 + nn) * 32 + dl) = pk;
      }
  } else {
    // Natural orientation: reg-dim = consecutive n -> contiguous in VT.
#pragma unroll
    for (int s = 0; s < 2; s++)
#pragma unroll
      for (int c = 0; c < 8; c++) {
        const int col = n0 + c * 16 + l15;  // h*32 + d
        const int hh = col >> 5, dl = col & 31;
        const int row = m0 + w * 32 + s * 16 + quad * 4;
        const int bb = row >> 12, nn = row & 4095;
        u32x2 pk = {pack_bf16(acc[s][c][0], acc[s][c][1]),
                    pack_bf16(acc[s][c][2], acc[s][c][3])};
        *(u32x2*)(VT + (size_t)((bb * 8 + hh) * 32 + dl) * 4096 + nn) = pk;
      }
  }
}

// ---------------------------------------------------------------------------
// Kernel 3: attention. Block = 512 threads (8 waves), one (b,h) x 512 q;
// wave owns 64 q (4 strips). Per iter: 64-key K-tile (4KB, [key][32d]) + V-tile
// (4KB, [d][64key] with 16B-seg XOR swizzle) staged into dbuf LDS — one
// global_load_lds_dwordx4 per wave (waves 0-3: K, 4-7: V). Loop order
// stage(i+1) -> compute(i) -> barrier hides the vmcnt drain behind compute.
// S^T = K·Q^T (C/D row=key=quad*4+reg), leaky+pack in regs, P^T feeds the
// K=16 PV MFMA directly. Direct f32x4 epilogue stores (no reduction).
// ---------------------------------------------------------------------------
__global__ __launch_bounds__(512, 2) void attn_kernel(
    const unsigned short* __restrict__ QH, const unsigned short* __restrict__ KH,
    const unsigned short* __restrict__ VT, float* __restrict__ out) {
  __shared__ __align__(16) char smem[16384];  // dbuf x (K 4K + V 4K)
  const int tid = threadIdx.x;
  const int w = tid >> 6, lane = tid & 63, l15 = lane & 15, quad = lane >> 4;
  const int bid = blockIdx.x;
  const int bh = bid & 31, qh = bid >> 5;  // XCD swizzle: bh fixed per XCD
  const int b = bh >> 3, h = bh & 7;
  const int qbase = qh * 512 + w * 64;

  // Q frags once (packed head layout -> contiguous 1KB wave loads).
  const unsigned short* Qp =
      QH + ((size_t)bh * 4096 + qbase + l15) * 32 + quad * 8;
  short8 qf[4];
#pragma unroll
  for (int s = 0; s < 4; s++) qf[s] = *(const short8*)(Qp + (size_t)s * 512);

  // Staging setup (per lane global src; wave-uniform LDS base).
  const bool isK = (w < 4);
  const unsigned short* src0;
  int kstr, wbOff;
  if (isK) {
    const int key = w * 16 + (lane >> 2), dseg = lane & 3;
    src0 = KH + ((size_t)bh * 4096 + key) * 32 + dseg * 8;
    kstr = 32;          // shorts per key step
    wbOff = w * 1024;   // K region
  } else {
    const int r = (w - 4) * 8 + (lane >> 3), useg = lane & 7;
    src0 = VT + ((size_t)bh * 32 + r) * 4096 + ((useg ^ (r & 7)) * 8);
    kstr = 1;
    wbOff = 4096 + (w - 4) * 1024;  // V region
  }

  async_cp16(src0, smem + wbOff);  // preload tile 0 -> buf 0
  __syncthreads();

  const f32x4 zero = {0.f, 0.f, 0.f, 0.f};
  f32x4 acc[4][2];  // O^T partials: col=q=l15(+16s), row=d=dt*16+quad*4+r
#pragma unroll
  for (int s = 0; s < 4; s++) {
    acc[s][0] = zero;
    acc[s][1] = zero;
  }

  const int rs = l15 & 7;
  for (int i = 0; i < 64; i++) {
    const int nb = i & 1;
    const int kn = ((i + 1) & 63) * 64;  // next key base (wraps, in-bounds)
    async_cp16(src0 + (size_t)kn * kstr, smem + (nb ^ 1) * 8192 + wbOff);

    const char* Kb = smem + nb * 8192;
    const char* Vb = Kb + 4096;
    short8 kf[4];
#pragma unroll
    for (int c = 0; c < 4; c++)
      kf[c] = *(const short8*)(Kb + (c * 16 + l15) * 64 + quad * 16);
    short4v vf[2][4];
#pragma unroll
    for (int dt = 0; dt < 2; dt++) {
      const char* Vr = Vb + (dt * 16 + l15) * 128 + (quad & 1) * 8;
#pragma unroll
      for (int c = 0; c < 4; c++) {
        const int tt = c * 2 + (quad >> 1);
        vf[dt][c] = *(const short4v*)(Vr + ((tt ^ rs) * 16));
      }
    }

#pragma unroll
    for (int s = 0; s < 4; s++) {
#pragma unroll
      for (int c = 0; c < 4; c++) {
        f32x4 st = MFMA16x32(kf[c], qf[s], zero);  // S^T 16key x 16q
        float t0 = fmaxf(st[0], 0.2f * st[0]);     // Q pre-scaled by 1/sqrt(dk)
        float t1 = fmaxf(st[1], 0.2f * st[1]);
        float t2 = fmaxf(st[2], 0.2f * st[2]);
        float t3 = fmaxf(st[3], 0.2f * st[3]);
        u32x2 pk = {pack_bf16(t0, t1), pack_bf16(t2, t3)};
        const short4v pb = __builtin_bit_cast(short4v, pk);
#pragma unroll
        for (int dt = 0; dt < 2; dt++)
          acc[s][dt] = mfma16x16(vf[dt][c], pb, acc[s][dt]);
      }
    }
    __syncthreads();
  }

  // Epilogue: out[b][q][h*32+d]; lane q=l15(+16s), d=dt*16+quad*4..+4.
#pragma unroll
  for (int s = 0; s < 4; s++)
#pragma unroll
    for (int dt = 0; dt < 2; dt++)
      *(f32x4*)(out + ((size_t)b * 4096 + qbase + s * 16 + l15) * 256 + h * 32 +
                dt * 16 + quad * 4) = acc[s][dt];
}

// ---------------------------------------------------------------------------
extern "C" void kernel_launch(void* const* d_in, const int* in_sizes, int n_in,
                              void* d_out, int out_size, void* d_ws,
                              size_t ws_size, hipStream_t stream) {
  const float* x = (const float*)d_in[0];
  const float* Wq = (const float*)d_in[1];
  const float* Wk = (const float*)d_in[2];
  const float* Wv = (const float*)d_in[3];
  float* out = (float*)d_out;

  // Workspace (bf16): QH | KH | VT | xb | WT   (~33.5 MB)
  unsigned short* ws = (unsigned short*)d_ws;
  unsigned short* QHb = ws;                // 32 bh * 4096 n * 32 d
  unsigned short* KHb = ws + 4194304;      // 32 bh * 4096 n * 32 d
  unsigned short* VTb = ws + 2 * 4194304;  // 32 bh * 32 d * 4096 n
  unsigned short* xbb = ws + 3 * 4194304;  // 16384*256
  unsigned short* WTb = ws + 4 * 4194304;  // 3 * 256 * 256

  xconv_kernel<<<4096, 256, 0, stream>>>(x, xbb);
  wtrans_kernel<<<192, 256, 0, stream>>>(Wq, Wk, Wv, WTb);
  proj_kernel<<<768, 256, 0, stream>>>(xbb, WTb, QHb, KHb, VTb);
  attn_kernel<<<256, 512, 0, stream>>>(QHb, KHb, VTb, out);
}